// Round 4
// baseline (29.049 us; speedup 1.0000x reference)
//
#include <hip/hip_runtime.h>

// Problem constants
#define N_MAX       128
#define NODE_VOCAB  128
#define EDGE_VOCAB  16
#define BATCH       256
#define SEQ         8256                   // N_MAX + N_MAX*(N_MAX-1)/2
#define N_EDGES     8128                   // SEQ - N_MAX

// Output layout (flat f32):
//   node_logits [B][N_MAX][NODE_VOCAB]   -> 256*128*128  = 4,194,304 floats
//   edge_logits [B][N_EDGES][EDGE_VOCAB] -> 256*8128*16  = 33,292,288 floats
#define NODE_FLOATS     (BATCH * N_MAX * NODE_VOCAB)
#define NODE_F_PER_B    (N_MAX * NODE_VOCAB)      // 16384 floats
#define EDGE_F_PER_B    (N_EDGES * EDGE_VOCAB)    // 130048 floats

// Per-batch float4 count: (16384 + 130048)/4 = 36608.
#define F4_PER_B        36608
#define NODE_F4_PER_B   4096

// Work per thread (float4 stores). Block covers 256*W = 1024 f4.
#define W 4
#define F4_PER_BLOCK (256 * W)
#define GRID_X ((F4_PER_B + F4_PER_BLOCK - 1) / F4_PER_BLOCK)   // 36

__global__ __launch_bounds__(256)
void fill_logits_kernel(const int* __restrict__ x0,
                        float* __restrict__ out) {
    const int b    = blockIdx.y;
    const int base = blockIdx.x * F4_PER_BLOCK + threadIdx.x;

    const int* __restrict__ xrow = x0 + (size_t)b * SEQ;

#pragma unroll
    for (int w = 0; w < W; ++w) {
        const int f = base + w * 256;        // f4 index within batch
        if (f < F4_PER_B) {
            int    x;     // target token for this row
            int    v0;    // first vocab index covered by this float4
            float* dst;

            if (f < NODE_F4_PER_B) {
                // node region (blocks 0..3 entirely; wave-uniform)
                const int i = f >> 5;                // node slot 0..127
                v0  = (f & 31) << 2;                 // vocab offset 0..124
                x   = xrow[i];
                dst = out + (size_t)b * NODE_F_PER_B + (size_t)f * 4;
            } else {
                // edge region (blocks 4..35)
                const int g = f - NODE_F4_PER_B;     // 0 .. 32511
                const int j = g >> 2;                // edge slot 0..8127
                v0  = (g & 3) << 2;                  // vocab offset 0,4,8,12
                x   = xrow[N_MAX + j];
                dst = out + NODE_FLOATS + (size_t)b * EDGE_F_PER_B + (size_t)g * 4;
            }

            float4 v;
            v.x = (x == v0 + 0) ? 100.0f : -100.0f;
            v.y = (x == v0 + 1) ? 100.0f : -100.0f;
            v.z = (x == v0 + 2) ? 100.0f : -100.0f;
            v.w = (x == v0 + 3) ? 100.0f : -100.0f;

            *reinterpret_cast<float4*>(dst) = v;
        }
    }
}

extern "C" void kernel_launch(void* const* d_in, const int* in_sizes, int n_in,
                              void* d_out, int out_size, void* d_ws, size_t ws_size,
                              hipStream_t stream) {
    const int* x0 = (const int*)d_in[0];   // [B, SEQ] int32 (harness-converted)
    float* out    = (float*)d_out;

    dim3 grid(GRID_X, BATCH);              // (36, 256) = 9216 blocks
    fill_logits_kernel<<<grid, 256, 0, stream>>>(x0, out);
}